// Round 12
// baseline (945.754 us; speedup 1.0000x reference)
//
#include <hip/hip_runtime.h>
#include <hip/hip_cooperative_groups.h>

namespace cg = cooperative_groups;

#define EPS_BN 1e-5f
#define HSTRIDE 68   // 64 dwords + 4 pad (272B rows, 16B-aligned)
#define BSH 9        // bucket = 512 consecutive nodes

typedef __attribute__((ext_vector_type(4))) float f32x4;
typedef __attribute__((ext_vector_type(8))) short s16x8;

__device__ inline unsigned short f2bf(float f) {
    unsigned int u = __float_as_uint(f);
    unsigned int r = (u + 0x7fffu + ((u >> 16) & 1u)) >> 16;
    return (unsigned short)r;
}
__device__ inline unsigned int packbf(float lo, float hi) {
    return (unsigned int)f2bf(lo) | ((unsigned int)f2bf(hi) << 16);
}
__device__ inline float bflo(unsigned int p) { return __uint_as_float(p << 16); }
__device__ inline float bfhi(unsigned int p) { return __uint_as_float(p & 0xffff0000u); }

// ====== combined prep: x->bf16, W1/W2 -> MFMA B-frags, bucket histogram ======
__global__ void k_prep_all(const float* __restrict__ x, unsigned int* __restrict__ xbf, int n8,
                           const float* __restrict__ W1, unsigned int* __restrict__ W1p,
                           const float* __restrict__ W2, unsigned int* __restrict__ W2p,
                           const int* __restrict__ dst, int* __restrict__ bCnt,
                           int e, int nhist) {
    __shared__ int cnt[256];
    int tid = threadIdx.x;
    bool hb = ((int)blockIdx.x < nhist);
    if (hb) cnt[tid] = 0;
    __syncthreads();
    int t = blockIdx.x * 256 + tid;
    if (t < n8) {
        float2 v = ((const float2*)x)[t];
        xbf[t] = packbf(v.x, v.y);
    }
    if (t < 8192) {
        int dj = t & 3;
        int lane = (t >> 2) & 63;
        int kc = (t >> 8) & 3;
        int ct = t >> 10;
        int quad = lane >> 4, mrow = lane & 15;
        int k0 = kc * 32 + quad * 8 + dj * 2;
        int col = ct * 16 + mrow;
        W1p[t] = packbf(W1[k0 * 128 + col], W1[(k0 + 1) * 128 + col]);
    }
    if (t < 1024) {
        int dj = t & 3;
        int lane = (t >> 2) & 63;
        int kc = t >> 8;
        int quad = lane >> 4, mrow = lane & 15;
        int k0 = kc * 32 + quad * 8 + dj * 2;
        float lo = (mrow < 12) ? W2[k0 * 12 + mrow] : 0.f;
        float hi = (mrow < 12) ? W2[(k0 + 1) * 12 + mrow] : 0.f;
        W2p[t] = packbf(lo, hi);
    }
    if (hb) {
        int base = blockIdx.x * 4096 + tid * 16;
        #pragma unroll
        for (int k = 0; k < 16; ++k) {
            int i = base + k;
            if (i < e) atomicAdd(&cnt[dst[i] >> BSH], 1);
        }
    }
    __syncthreads();
    if (hb) {
        int c = cnt[tid];
        if (c) atomicAdd(&bCnt[tid], c);
    }
}

// exclusive scan of bucket counts -> bucketBase, init cursors; zero BN stat buffers
__global__ void k_scan_buckets(const int* __restrict__ bucketCnt, int* __restrict__ bucketBase,
                               int* __restrict__ bucketCursor, int nb, int e,
                               float* __restrict__ stat0, float* __restrict__ stat1) {
    __shared__ int s[256];
    int t = threadIdx.x;
    stat0[t] = 0.f;
    stat1[t] = 0.f;
    int v = (t < nb) ? bucketCnt[t] : 0;
    s[t] = v;
    __syncthreads();
    for (int off = 1; off < 256; off <<= 1) {
        int u = (t >= off) ? s[t - off] : 0;
        __syncthreads();
        s[t] += u;
        __syncthreads();
    }
    int excl = s[t] - v;
    if (t < nb) { bucketBase[t] = excl; bucketCursor[t] = excl; }
    if (t == 0) bucketBase[nb] = e;
}

// pass 2: scatter edges into bucket-partitioned etmp, coalesced via LDS staging.
__global__ void k_pass2(const int* __restrict__ src, const int* __restrict__ dst,
                        const float* __restrict__ w, int* __restrict__ bucketCursor,
                        uint2* __restrict__ etmp, int e) {
    __shared__ int cnt[256];
    __shared__ int s[256];
    __shared__ int gbase[256];
    __shared__ int lscan[256];
    __shared__ uint2 rec[2048];
    __shared__ unsigned short bof[2048];
    int t = threadIdx.x;
    cnt[t] = 0;
    __syncthreads();
    int base = blockIdx.x * 2048;
    int myB[8], myR[8];
    unsigned int mySrc[8], myW[8];
    int myDl[8];
    #pragma unroll
    for (int k = 0; k < 8; ++k) {
        int i = base + t * 8 + k;
        if (i < e) {
            int d = dst[i];
            myB[k] = d >> BSH;
            myDl[k] = d & 511;
            mySrc[k] = (unsigned int)src[i];
            myW[k] = __float_as_uint(w[i]);
            myR[k] = atomicAdd(&cnt[myB[k]], 1);
        } else {
            myB[k] = -1;
        }
    }
    __syncthreads();
    int c = cnt[t];
    s[t] = c;
    __syncthreads();
    for (int off = 1; off < 256; off <<= 1) {
        int u = (t >= off) ? s[t - off] : 0;
        __syncthreads();
        s[t] += u;
        __syncthreads();
    }
    lscan[t] = s[t] - c;
    if (c > 0) gbase[t] = atomicAdd(&bucketCursor[t], c);
    __syncthreads();
    #pragma unroll
    for (int k = 0; k < 8; ++k) {
        if (myB[k] >= 0) {
            int lpos = lscan[myB[k]] + myR[k];
            rec[lpos] = make_uint2(mySrc[k] | ((unsigned int)myDl[k] << 17), myW[k]);
            bof[lpos] = (unsigned short)myB[k];
        }
    }
    __syncthreads();
    int m = e - base; if (m > 2048) m = 2048;
    for (int i = t; i < m; i += 256) {
        int b = bof[i];
        etmp[gbase[b] + (i - lscan[b])] = rec[i];
    }
}

// pass 3: per-bucket local CSR + degree -> dinv. One block per bucket (512 nodes).
__global__ void k_pass3(const uint2* __restrict__ etmp, const int* __restrict__ bucketBase,
                        int* __restrict__ R, uint2* __restrict__ epair,
                        float* __restrict__ dinv, int n) {
    __shared__ int hist[512];
    __shared__ float degs[512];
    __shared__ int s[256];
    int b = blockIdx.x, t = threadIdx.x;
    int lo = bucketBase[b], hi = bucketBase[b + 1];
    hist[t] = 0; hist[t + 256] = 0;
    degs[t] = 0.f; degs[t + 256] = 0.f;
    __syncthreads();
    for (int i = lo + t; i < hi; i += 256)
        atomicAdd(&hist[etmp[i].x >> 17], 1);
    __syncthreads();
    int c0 = hist[2 * t], c1 = hist[2 * t + 1];
    int p = c0 + c1;
    s[t] = p;
    __syncthreads();
    for (int off = 1; off < 256; off <<= 1) {
        int u = (t >= off) ? s[t - off] : 0;
        __syncthreads();
        s[t] += u;
        __syncthreads();
    }
    int excl = s[t] - p;
    int node0 = b << BSH;
    int e0 = excl, e1 = excl + c0;
    if (node0 + 2 * t < n)     R[node0 + 2 * t]     = lo + e0;
    if (node0 + 2 * t + 1 < n) R[node0 + 2 * t + 1] = lo + e1;
    __syncthreads();
    hist[2 * t] = e0; hist[2 * t + 1] = e1;   // cursors
    __syncthreads();
    for (int i = lo + t; i < hi; i += 256) {
        uint2 r = etmp[i];
        int dl = r.x >> 17;
        int slot = lo + atomicAdd(&hist[dl], 1);
        epair[slot] = make_uint2(r.x & 0x1FFFFu, r.y);
        atomicAdd(&degs[dl], __uint_as_float(r.y));
    }
    __syncthreads();
    for (int l = t; l < 512; l += 256) {
        int node = node0 + l;
        if (node < n) dinv[node] = rsqrtf(1.f + degs[l]);
    }
}

// ================= shared-LDS union for cooperative kernels =================
struct L0Sh { float Ws[16 * 128]; float xs[32 * 16]; };
struct GemmSh { unsigned int hsbf[64 * HSTRIDE]; float sc[128]; float sh[128]; };
union CoopSh { L0Sh l0; GemmSh gm; };

// ====== coop1: layer0 (agg_x + GEMM16->128) -> BN0 stats -> MFMA gemm_hid ======
__global__ __launch_bounds__(256, 4) void k_coop1(
        const unsigned int* __restrict__ xbf, const uint2* __restrict__ epair,
        const int* __restrict__ R, const float* __restrict__ dinv,
        const float* __restrict__ W0, const float* __restrict__ b0,
        unsigned int* __restrict__ Bbf, float* __restrict__ stat0,
        const float* __restrict__ g0, const float* __restrict__ be0,
        const unsigned int* __restrict__ W1p, unsigned int* __restrict__ Abf,
        int n, int e, float invn) {
    cg::grid_group grid = cg::this_grid();
    __shared__ CoopSh su;
    int tid = threadIdx.x;

    // ---- phase L0: 32 nodes per tile ----
    {
        for (int i = tid; i < 2048; i += 256) su.l0.Ws[i] = W0[i];
        int ntiles = (n + 31) / 32;
        for (int tile = blockIdx.x; tile < ntiles; tile += gridDim.x) {
            int node0 = tile * 32;
            __syncthreads();   // Ws ready first iter; xs reuse safe after GEMM reads
            int node_l = tid >> 3, u = tid & 7;
            int node = node0 + node_l;
            if (node < n) {
                int start = R[node];
                int end = (node + 1 < n) ? R[node + 1] : e;
                float ax = 0.f, ay = 0.f;
                int j = start;
                for (; j + 3 < end; j += 4) {
                    uint2 p0 = epair[j], p1 = epair[j + 1], p2 = epair[j + 2], p3 = epair[j + 3];
                    float w0 = dinv[p0.x] * __uint_as_float(p0.y);
                    float w1 = dinv[p1.x] * __uint_as_float(p1.y);
                    float w2 = dinv[p2.x] * __uint_as_float(p2.y);
                    float w3 = dinv[p3.x] * __uint_as_float(p3.y);
                    unsigned int q0 = xbf[(size_t)p0.x * 8 + u];
                    unsigned int q1 = xbf[(size_t)p1.x * 8 + u];
                    unsigned int q2 = xbf[(size_t)p2.x * 8 + u];
                    unsigned int q3 = xbf[(size_t)p3.x * 8 + u];
                    ax += bflo(q0) * w0 + bflo(q1) * w1 + bflo(q2) * w2 + bflo(q3) * w3;
                    ay += bfhi(q0) * w0 + bfhi(q1) * w1 + bfhi(q2) * w2 + bfhi(q3) * w3;
                }
                for (; j < end; ++j) {
                    uint2 p0 = epair[j];
                    float w0 = dinv[p0.x] * __uint_as_float(p0.y);
                    unsigned int q0 = xbf[(size_t)p0.x * 8 + u];
                    ax += bflo(q0) * w0;
                    ay += bfhi(q0) * w0;
                }
                float di = dinv[node];
                unsigned int ps = xbf[(size_t)node * 8 + u];
                su.l0.xs[node_l * 16 + 2 * u]     = ax * di + bflo(ps) * di * di;
                su.l0.xs[node_l * 16 + 2 * u + 1] = ay * di + bfhi(ps) * di * di;
            }
            __syncthreads();
            int f = tid & 127, half = tid >> 7;
            float bf = b0[f];
            for (int nl = 0; nl < 16; ++nl) {
                int nloc = half * 16 + nl;
                int gn = node0 + nloc;
                float acc = bf;
                #pragma unroll
                for (int k = 0; k < 16; ++k) acc += su.l0.xs[nloc * 16 + k] * su.l0.Ws[k * 128 + f];
                float hi = __shfl_xor(acc, 1);
                if ((f & 1) == 0 && gn < n)
                    Bbf[(size_t)gn * 64 + (f >> 1)] = packbf(acc, hi);
            }
        }
    }
    grid.sync();

    // ---- phase S0: BN stats of Bbf -> stat0 ----
    {
        int u = tid & 63, q = tid >> 6;
        int nchunk = (n + 255) / 256;
        for (int chunk = blockIdx.x; chunk < nchunk; chunk += gridDim.x) {
            int i1 = chunk * 256 + 256; if (i1 > n) i1 = n;
            float sl = 0.f, shh = 0.f, ql = 0.f, qh = 0.f;
            for (int i = chunk * 256 + q; i < i1; i += 4) {
                unsigned int p = Bbf[(size_t)i * 64 + u];
                float lo = bflo(p), hi = bfhi(p);
                sl += lo; ql += lo * lo;
                shh += hi; qh += hi * hi;
            }
            atomicAdd(&stat0[2 * u], sl);
            atomicAdd(&stat0[2 * u + 1], shh);
            atomicAdd(&stat0[128 + 2 * u], ql);
            atomicAdd(&stat0[128 + 2 * u + 1], qh);
        }
    }
    grid.sync();

    // ---- phase GH: BN0+ReLU fused MFMA gemm_hid ----
    {
        if (tid < 128) {
            float m = stat0[tid] * invn;
            float v = stat0[128 + tid] * invn - m * m;
            float scale = rsqrtf(v + EPS_BN) * g0[tid];
            su.gm.sc[tid] = scale;
            su.gm.sh[tid] = be0[tid] - m * scale;
        }
        const uint4* Bbf4 = (const uint4*)Bbf;
        int ntile = (n + 63) / 64;
        int wave = tid >> 6, lane = tid & 63;
        int quad = lane >> 4, mrow = lane & 15;
        const s16x8* Wf = (const s16x8*)W1p;
        for (int tile = blockIdx.x; tile < ntile; tile += gridDim.x) {
            int node0 = tile * 64;
            __syncthreads();   // sc/sh ready; hsbf reuse safe
            for (int i = tid; i < 64 * 16; i += 256) {
                int row = i >> 4, q = i & 15;
                int gn = node0 + row;
                uint4 pk;
                if (gn < n) {
                    uint4 p = Bbf4[(size_t)gn * 16 + q];
                    int fb = q * 8;
                    float v0 = fmaxf(bflo(p.x) * su.gm.sc[fb + 0] + su.gm.sh[fb + 0], 0.f);
                    float v1 = fmaxf(bfhi(p.x) * su.gm.sc[fb + 1] + su.gm.sh[fb + 1], 0.f);
                    float v2 = fmaxf(bflo(p.y) * su.gm.sc[fb + 2] + su.gm.sh[fb + 2], 0.f);
                    float v3 = fmaxf(bfhi(p.y) * su.gm.sc[fb + 3] + su.gm.sh[fb + 3], 0.f);
                    float v4 = fmaxf(bflo(p.z) * su.gm.sc[fb + 4] + su.gm.sh[fb + 4], 0.f);
                    float v5 = fmaxf(bfhi(p.z) * su.gm.sc[fb + 5] + su.gm.sh[fb + 5], 0.f);
                    float v6 = fmaxf(bflo(p.w) * su.gm.sc[fb + 6] + su.gm.sh[fb + 6], 0.f);
                    float v7 = fmaxf(bfhi(p.w) * su.gm.sc[fb + 7] + su.gm.sh[fb + 7], 0.f);
                    pk = make_uint4(packbf(v0, v1), packbf(v2, v3), packbf(v4, v5), packbf(v6, v7));
                } else {
                    pk = make_uint4(0u, 0u, 0u, 0u);
                }
                *((uint4*)&su.gm.hsbf[row * HSTRIDE + q * 4]) = pk;
            }
            __syncthreads();
            int lrow = wave * 16 + mrow;
            s16x8 afrag[4];
            #pragma unroll
            for (int kc = 0; kc < 4; ++kc)
                afrag[kc] = *((const s16x8*)&su.gm.hsbf[lrow * HSTRIDE + kc * 16 + quad * 4]);
            int gnode_base = node0 + wave * 16;
            for (int ct = 0; ct < 8; ++ct) {
                f32x4 acc = {0.f, 0.f, 0.f, 0.f};
                #pragma unroll
                for (int kc = 0; kc < 4; ++kc) {
                    s16x8 bfrag = Wf[(ct * 4 + kc) * 64 + lane];
                    acc = __builtin_amdgcn_mfma_f32_16x16x32_bf16(afrag[kc], bfrag, acc, 0, 0, 0);
                }
                #pragma unroll
                for (int r = 0; r < 4; ++r) {
                    float lo = acc[r];
                    float hi = __shfl_xor(lo, 1);
                    int grow = gnode_base + quad * 4 + r;
                    if ((mrow & 1) == 0 && grow < n)
                        Abf[(size_t)grow * 64 + ct * 8 + (mrow >> 1)] = packbf(lo, hi);
                }
            }
        }
    }
}

// layer-1: 128-feature bf16 aggregation (standalone — occupancy-critical).
__global__ void k_aggregate128(const uint4* __restrict__ Abf4, const uint2* __restrict__ epair,
                               const int* __restrict__ R, const float* __restrict__ dinv,
                               const float4* __restrict__ bias4, uint4* __restrict__ Bbf4,
                               int n, int e) {
    int gid = blockIdx.x * blockDim.x + threadIdx.x;
    int node = gid >> 6;
    if (node >= n) return;
    int lane = threadIdx.x & 63;
    int grp = lane >> 4, sub = lane & 15;
    int start = R[node];
    int end = (node + 1 < n) ? R[node + 1] : e;
    float a[8] = {0.f, 0.f, 0.f, 0.f, 0.f, 0.f, 0.f, 0.f};
    for (int base = start; base < end; base += 64) {
        int m = end - base; if (m > 64) m = 64;
        int myS = 0; float myW = 0.f;
        if (lane < m) {
            uint2 pr = epair[base + lane];
            myS = (int)pr.x;
            myW = dinv[pr.x] * __uint_as_float(pr.y);
        }
        for (int t = 0; t < m; t += 16) {
            int j0 = t + grp, j1 = t + 4 + grp, j2 = t + 8 + grp, j3 = t + 12 + grp;
            int s0 = __shfl(myS, j0); float w0 = __shfl(myW, j0);
            int s1 = __shfl(myS, j1); float w1 = __shfl(myW, j1);
            int s2 = __shfl(myS, j2); float w2 = __shfl(myW, j2);
            int s3 = __shfl(myS, j3); float w3 = __shfl(myW, j3);
            if (j0 < m) {
                uint4 p = Abf4[(size_t)s0 * 16 + sub];
                a[0] += bflo(p.x) * w0; a[1] += bfhi(p.x) * w0;
                a[2] += bflo(p.y) * w0; a[3] += bfhi(p.y) * w0;
                a[4] += bflo(p.z) * w0; a[5] += bfhi(p.z) * w0;
                a[6] += bflo(p.w) * w0; a[7] += bfhi(p.w) * w0;
            }
            if (j1 < m) {
                uint4 p = Abf4[(size_t)s1 * 16 + sub];
                a[0] += bflo(p.x) * w1; a[1] += bfhi(p.x) * w1;
                a[2] += bflo(p.y) * w1; a[3] += bfhi(p.y) * w1;
                a[4] += bflo(p.z) * w1; a[5] += bfhi(p.z) * w1;
                a[6] += bflo(p.w) * w1; a[7] += bfhi(p.w) * w1;
            }
            if (j2 < m) {
                uint4 p = Abf4[(size_t)s2 * 16 + sub];
                a[0] += bflo(p.x) * w2; a[1] += bfhi(p.x) * w2;
                a[2] += bflo(p.y) * w2; a[3] += bfhi(p.y) * w2;
                a[4] += bflo(p.z) * w2; a[5] += bfhi(p.z) * w2;
                a[6] += bflo(p.w) * w2; a[7] += bfhi(p.w) * w2;
            }
            if (j3 < m) {
                uint4 p = Abf4[(size_t)s3 * 16 + sub];
                a[0] += bflo(p.x) * w3; a[1] += bfhi(p.x) * w3;
                a[2] += bflo(p.y) * w3; a[3] += bfhi(p.y) * w3;
                a[4] += bflo(p.z) * w3; a[5] += bfhi(p.z) * w3;
                a[6] += bflo(p.w) * w3; a[7] += bfhi(p.w) * w3;
            }
        }
    }
    #pragma unroll
    for (int k = 0; k < 8; ++k) {
        a[k] += __shfl_xor(a[k], 16);
        a[k] += __shfl_xor(a[k], 32);
    }
    if (grp == 0) {
        float di = dinv[node];
        uint4 ps = Abf4[(size_t)node * 16 + sub];
        float4 bl = bias4[2 * sub], bh = bias4[2 * sub + 1];
        float r0 = a[0] * di + bflo(ps.x) * di * di + bl.x;
        float r1 = a[1] * di + bfhi(ps.x) * di * di + bl.y;
        float r2 = a[2] * di + bflo(ps.y) * di * di + bl.z;
        float r3 = a[3] * di + bfhi(ps.y) * di * di + bl.w;
        float r4 = a[4] * di + bflo(ps.z) * di * di + bh.x;
        float r5 = a[5] * di + bfhi(ps.z) * di * di + bh.y;
        float r6 = a[6] * di + bflo(ps.w) * di * di + bh.z;
        float r7 = a[7] * di + bfhi(ps.w) * di * di + bh.w;
        Bbf4[(size_t)node * 16 + sub] = make_uint4(packbf(r0, r1), packbf(r2, r3),
                                                   packbf(r4, r5), packbf(r6, r7));
    }
}

// ====== coop2: BN1 stats -> MFMA gemm_out -> agg_out ======
__global__ __launch_bounds__(256, 4) void k_coop2(
        const unsigned int* __restrict__ Bbf, float* __restrict__ stat1,
        const float* __restrict__ g1, const float* __restrict__ be1,
        const unsigned int* __restrict__ W2p, unsigned int* __restrict__ A16bf,
        const uint2* __restrict__ epair, const int* __restrict__ R,
        const float* __restrict__ dinv, const float* __restrict__ b2,
        float* __restrict__ out, int n, int e, float invn) {
    cg::grid_group grid = cg::this_grid();
    __shared__ GemmSh su;
    int tid = threadIdx.x;

    // ---- phase S1: BN stats of Bbf -> stat1 ----
    {
        int u = tid & 63, q = tid >> 6;
        int nchunk = (n + 255) / 256;
        for (int chunk = blockIdx.x; chunk < nchunk; chunk += gridDim.x) {
            int i1 = chunk * 256 + 256; if (i1 > n) i1 = n;
            float sl = 0.f, shh = 0.f, ql = 0.f, qh = 0.f;
            for (int i = chunk * 256 + q; i < i1; i += 4) {
                unsigned int p = Bbf[(size_t)i * 64 + u];
                float lo = bflo(p), hi = bfhi(p);
                sl += lo; ql += lo * lo;
                shh += hi; qh += hi * hi;
            }
            atomicAdd(&stat1[2 * u], sl);
            atomicAdd(&stat1[2 * u + 1], shh);
            atomicAdd(&stat1[128 + 2 * u], ql);
            atomicAdd(&stat1[128 + 2 * u + 1], qh);
        }
    }
    grid.sync();

    // ---- phase GO: BN1+ReLU fused MFMA gemm_out ----
    {
        if (tid < 128) {
            float m = stat1[tid] * invn;
            float v = stat1[128 + tid] * invn - m * m;
            float scale = rsqrtf(v + EPS_BN) * g1[tid];
            su.sc[tid] = scale;
            su.sh[tid] = be1[tid] - m * scale;
        }
        const uint4* Bbf4 = (const uint4*)Bbf;
        int ntile = (n + 63) / 64;
        int wave = tid >> 6, lane = tid & 63;
        int quad = lane >> 4, mrow = lane & 15;
        const s16x8* Wf = (const s16x8*)W2p;
        for (int tile = blockIdx.x; tile < ntile; tile += gridDim.x) {
            int node0 = tile * 64;
            __syncthreads();
            for (int i = tid; i < 64 * 16; i += 256) {
                int row = i >> 4, q = i & 15;
                int gn = node0 + row;
                uint4 pk;
                if (gn < n) {
                    uint4 p = Bbf4[(size_t)gn * 16 + q];
                    int fb = q * 8;
                    float v0 = fmaxf(bflo(p.x) * su.sc[fb + 0] + su.sh[fb + 0], 0.f);
                    float v1 = fmaxf(bfhi(p.x) * su.sc[fb + 1] + su.sh[fb + 1], 0.f);
                    float v2 = fmaxf(bflo(p.y) * su.sc[fb + 2] + su.sh[fb + 2], 0.f);
                    float v3 = fmaxf(bfhi(p.y) * su.sc[fb + 3] + su.sh[fb + 3], 0.f);
                    float v4 = fmaxf(bflo(p.z) * su.sc[fb + 4] + su.sh[fb + 4], 0.f);
                    float v5 = fmaxf(bfhi(p.z) * su.sc[fb + 5] + su.sh[fb + 5], 0.f);
                    float v6 = fmaxf(bflo(p.w) * su.sc[fb + 6] + su.sh[fb + 6], 0.f);
                    float v7 = fmaxf(bfhi(p.w) * su.sc[fb + 7] + su.sh[fb + 7], 0.f);
                    pk = make_uint4(packbf(v0, v1), packbf(v2, v3), packbf(v4, v5), packbf(v6, v7));
                } else {
                    pk = make_uint4(0u, 0u, 0u, 0u);
                }
                *((uint4*)&su.hsbf[row * HSTRIDE + q * 4]) = pk;
            }
            __syncthreads();
            int lrow = wave * 16 + mrow;
            s16x8 afrag[4];
            #pragma unroll
            for (int kc = 0; kc < 4; ++kc)
                afrag[kc] = *((const s16x8*)&su.hsbf[lrow * HSTRIDE + kc * 16 + quad * 4]);
            int gnode_base = node0 + wave * 16;
            f32x4 acc = {0.f, 0.f, 0.f, 0.f};
            #pragma unroll
            for (int kc = 0; kc < 4; ++kc) {
                s16x8 bfrag = Wf[kc * 64 + lane];
                acc = __builtin_amdgcn_mfma_f32_16x16x32_bf16(afrag[kc], bfrag, acc, 0, 0, 0);
            }
            #pragma unroll
            for (int r = 0; r < 4; ++r) {
                float lo = acc[r];
                float hi = __shfl_xor(lo, 1);
                int grow = gnode_base + quad * 4 + r;
                if ((mrow & 1) == 0 && grow < n)
                    A16bf[(size_t)grow * 8 + (mrow >> 1)] = packbf(lo, hi);
            }
        }
    }
    grid.sync();

    // ---- phase AO: 12-feature aggregation to out ----
    {
        int node_l = tid >> 3, u = tid & 7;
        int ngrp = (n + 31) / 32;
        for (int grp = blockIdx.x; grp < ngrp; grp += gridDim.x) {
            int node = grp * 32 + node_l;
            if (node >= n || u >= 6) continue;
            int start = R[node];
            int end = (node + 1 < n) ? R[node + 1] : e;
            float ax = 0.f, ay = 0.f;
            int j = start;
            for (; j + 3 < end; j += 4) {
                uint2 p0 = epair[j], p1 = epair[j + 1], p2 = epair[j + 2], p3 = epair[j + 3];
                float w0 = dinv[p0.x] * __uint_as_float(p0.y);
                float w1 = dinv[p1.x] * __uint_as_float(p1.y);
                float w2 = dinv[p2.x] * __uint_as_float(p2.y);
                float w3 = dinv[p3.x] * __uint_as_float(p3.y);
                unsigned int q0 = A16bf[(size_t)p0.x * 8 + u];
                unsigned int q1 = A16bf[(size_t)p1.x * 8 + u];
                unsigned int q2 = A16bf[(size_t)p2.x * 8 + u];
                unsigned int q3 = A16bf[(size_t)p3.x * 8 + u];
                ax += bflo(q0) * w0 + bflo(q1) * w1 + bflo(q2) * w2 + bflo(q3) * w3;
                ay += bfhi(q0) * w0 + bfhi(q1) * w1 + bfhi(q2) * w2 + bfhi(q3) * w3;
            }
            for (; j < end; ++j) {
                uint2 p0 = epair[j];
                float w0 = dinv[p0.x] * __uint_as_float(p0.y);
                unsigned int q0 = A16bf[(size_t)p0.x * 8 + u];
                ax += bflo(q0) * w0;
                ay += bfhi(q0) * w0;
            }
            float di = dinv[node];
            unsigned int ps = A16bf[(size_t)node * 8 + u];
            ax = ax * di + bflo(ps) * di * di + b2[2 * u];
            ay = ay * di + bfhi(ps) * di * di + b2[2 * u + 1];
            ((float2*)(out + (size_t)node * 12))[u] = make_float2(ax, ay);
        }
    }
}

// ================= launch =================
extern "C" void kernel_launch(void* const* d_in, const int* in_sizes, int n_in,
                              void* d_out, int out_size, void* d_ws, size_t ws_size,
                              hipStream_t stream) {
    const float* x   = (const float*)d_in[0];
    const int*   ei  = (const int*)d_in[1];
    const float* ew  = (const float*)d_in[2];
    const float* W0  = (const float*)d_in[3];
    const float* b0  = (const float*)d_in[4];
    const float* W1  = (const float*)d_in[5];
    const float* b1  = (const float*)d_in[6];
    const float* W2  = (const float*)d_in[7];
    const float* b2  = (const float*)d_in[8];
    const float* g0  = (const float*)d_in[9];
    const float* be0 = (const float*)d_in[10];
    const float* g1  = (const float*)d_in[11];
    const float* be1 = (const float*)d_in[12];
    float* out = (float*)d_out;

    int n = in_sizes[0] / 16;   // 100000
    int e = in_sizes[2];        // 1600000
    const int* src = ei;
    const int* dst = ei + e;
    const int NB = (n + 511) >> 9;
    const int NHIST = (e + 4095) / 4096;

    // workspace layout (4B elems); etmp aliases B region (dead before Bbf written)
    float*        wsf   = (float*)d_ws;
    float*        dinv  = wsf;                                    // n
    int*          R     = (int*)(wsf + n);                        // n+4
    int*          bCnt  = R + (n + 4);                            // 512
    int*          bBase = bCnt + 512;                             // 520
    int*          bCur  = bBase + 520;                            // 512
    uint2*        epair = (uint2*)(bCur + 512);                   // e pairs
    float*        B     = (float*)(bCur + 512 + 2 * (size_t)e);   // region (n*128 dwords)
    uint2*        etmp  = (uint2*)B;                              // e pairs, aliases B
    unsigned int* Bbf   = (unsigned int*)B;                       // n*64 (bf16 packed)
    unsigned int* Abf   = (unsigned int*)(B + (size_t)n * 128);   // n*64
    unsigned int* xbf   = Abf + (size_t)n * 64;                   // n*8
    unsigned int* A16bf = xbf + (size_t)n * 8;                    // n*8
    float*        stat0 = (float*)(A16bf + (size_t)n * 8);        // 256
    float*        stat1 = stat0 + 256;                            // 256
    unsigned int* W1p   = (unsigned int*)(stat1 + 256);           // 8192
    unsigned int* W2p   = W1p + 8192;                             // 1024

    float invn = 1.0f / (float)n;

    // runtime-sized cooperative grids (host-side queries; graph-capture-safe)
    int dev = 0;
    hipGetDevice(&dev);
    hipDeviceProp_t prop;
    hipGetDeviceProperties(&prop, dev);
    int nb1 = 0, nb2 = 0;
    hipOccupancyMaxActiveBlocksPerMultiprocessor(&nb1, (const void*)k_coop1, 256, 0);
    hipOccupancyMaxActiveBlocksPerMultiprocessor(&nb2, (const void*)k_coop2, 256, 0);
    if (nb1 < 1) nb1 = 1;
    if (nb2 < 1) nb2 = 1;
    int grid1 = nb1 * prop.multiProcessorCount;
    int grid2 = nb2 * prop.multiProcessorCount;

    // ---- build + prep ----
    hipMemsetAsync(bCnt, 0, 512 * sizeof(int), stream);
    k_prep_all<<<(n * 8 + 255) / 256, 256, 0, stream>>>(x, xbf, n * 8, W1, W1p, W2, W2p,
                                                        dst, bCnt, e, NHIST);
    k_scan_buckets<<<1, 256, 0, stream>>>(bCnt, bBase, bCur, NB, e, stat0, stat1);
    k_pass2<<<(e + 2047) / 2048, 256, 0, stream>>>(src, dst, ew, bCur, etmp, e);
    k_pass3<<<NB, 256, 0, stream>>>(etmp, bBase, R, epair, dinv, n);

    // ---- coop1: layer0 + BN0-stats + gemm_hid ----
    {
        void* args[] = {(void*)&xbf, (void*)&epair, (void*)&R, (void*)&dinv, (void*)&W0,
                        (void*)&b0, (void*)&Bbf, (void*)&stat0, (void*)&g0, (void*)&be0,
                        (void*)&W1p, (void*)&Abf, (void*)&n, (void*)&e, (void*)&invn};
        hipLaunchCooperativeKernel((const void*)k_coop1, dim3(grid1), dim3(256),
                                   args, 0, stream);
    }

    // ---- aggregation (standalone, occupancy-critical) ----
    k_aggregate128<<<(n * 64 + 255) / 256, 256, 0, stream>>>((const uint4*)Abf, epair, R, dinv,
                                                             (const float4*)b1, (uint4*)Bbf, n, e);

    // ---- coop2: BN1-stats + gemm_out + agg_out ----
    {
        void* args[] = {(void*)&Bbf, (void*)&stat1, (void*)&g1, (void*)&be1, (void*)&W2p,
                        (void*)&A16bf, (void*)&epair, (void*)&R, (void*)&dinv, (void*)&b2,
                        (void*)&out, (void*)&n, (void*)&e, (void*)&invn};
        hipLaunchCooperativeKernel((const void*)k_coop2, dim3(grid2), dim3(256),
                                   args, 0, stream);
    }
}

// Round 13
// 544.168 us; speedup vs baseline: 1.7380x; 1.7380x over previous
//
#include <hip/hip_runtime.h>

#define EPS_BN 1e-5f
#define HSTRIDE 68   // 64 dwords + 4 pad (272B rows, 16B-aligned)
#define BSH 9        // bucket = 512 consecutive nodes

typedef __attribute__((ext_vector_type(4))) float f32x4;
typedef __attribute__((ext_vector_type(8))) short s16x8;

__device__ inline unsigned short f2bf(float f) {
    unsigned int u = __float_as_uint(f);
    unsigned int r = (u + 0x7fffu + ((u >> 16) & 1u)) >> 16;
    return (unsigned short)r;
}
__device__ inline unsigned int packbf(float lo, float hi) {
    return (unsigned int)f2bf(lo) | ((unsigned int)f2bf(hi) << 16);
}
__device__ inline float bflo(unsigned int p) { return __uint_as_float(p << 16); }
__device__ inline float bfhi(unsigned int p) { return __uint_as_float(p & 0xffff0000u); }

// ====== prep: x->bf16, W1/W2 -> MFMA B-frags, per-block bucket histogram ======
__global__ void k_prep_all(const float* __restrict__ x, unsigned int* __restrict__ xbf, int n8,
                           const float* __restrict__ W1, unsigned int* __restrict__ W1p,
                           const float* __restrict__ W2, unsigned int* __restrict__ W2p,
                           const int* __restrict__ dst, int* __restrict__ bHist,
                           int e, int nhist) {
    __shared__ int cnt[256];
    int tid = threadIdx.x;
    bool hb = ((int)blockIdx.x < nhist);
    if (hb) cnt[tid] = 0;
    __syncthreads();
    int t = blockIdx.x * 256 + tid;
    if (t < n8) {
        float2 v = ((const float2*)x)[t];
        xbf[t] = packbf(v.x, v.y);
    }
    if (t < 8192) {
        int dj = t & 3;
        int lane = (t >> 2) & 63;
        int kc = (t >> 8) & 3;
        int ct = t >> 10;
        int quad = lane >> 4, mrow = lane & 15;
        int k0 = kc * 32 + quad * 8 + dj * 2;
        int col = ct * 16 + mrow;
        W1p[t] = packbf(W1[k0 * 128 + col], W1[(k0 + 1) * 128 + col]);
    }
    if (t < 1024) {
        int dj = t & 3;
        int lane = (t >> 2) & 63;
        int kc = t >> 8;
        int quad = lane >> 4, mrow = lane & 15;
        int k0 = kc * 32 + quad * 8 + dj * 2;
        float lo = (mrow < 12) ? W2[k0 * 12 + mrow] : 0.f;
        float hi = (mrow < 12) ? W2[(k0 + 1) * 12 + mrow] : 0.f;
        W2p[t] = packbf(lo, hi);
    }
    if (hb) {
        int base = blockIdx.x * 4096 + tid * 16;
        #pragma unroll
        for (int k = 0; k < 16; ++k) {
            int i = base + k;
            if (i < e) atomicAdd(&cnt[dst[i] >> BSH], 1);
        }
    }
    __syncthreads();
    if (hb) bHist[blockIdx.x * 256 + tid] = cnt[tid];   // plain store, no global atomics
}

// reduce per-block hists -> exclusive scan -> bucketBase/cursors; zero BN stats
__global__ void k_reduce_scan(const int* __restrict__ bHist, int* __restrict__ bucketBase,
                              int* __restrict__ bucketCursor, int nb, int e, int nhist,
                              float* __restrict__ stat0, float* __restrict__ stat1) {
    __shared__ int s[256];
    int t = threadIdx.x;
    stat0[t] = 0.f;
    stat1[t] = 0.f;
    int v = 0;
    for (int b = 0; b < nhist; ++b) v += bHist[b * 256 + t];
    if (t >= nb) v = 0;
    s[t] = v;
    __syncthreads();
    for (int off = 1; off < 256; off <<= 1) {
        int u = (t >= off) ? s[t - off] : 0;
        __syncthreads();
        s[t] += u;
        __syncthreads();
    }
    int excl = s[t] - v;
    if (t < nb) { bucketBase[t] = excl; bucketCursor[t] = excl; }
    if (t == 0) bucketBase[nb] = e;
}

// pass 2: scatter edges into bucket-partitioned etmp, coalesced via LDS staging.
__global__ void k_pass2(const int* __restrict__ src, const int* __restrict__ dst,
                        const float* __restrict__ w, int* __restrict__ bucketCursor,
                        uint2* __restrict__ etmp, int e) {
    __shared__ int cnt[256];
    __shared__ int s[256];
    __shared__ int gbase[256];
    __shared__ int lscan[256];
    __shared__ uint2 rec[2048];
    __shared__ unsigned short bof[2048];
    int t = threadIdx.x;
    cnt[t] = 0;
    __syncthreads();
    int base = blockIdx.x * 2048;
    int myB[8], myR[8];
    unsigned int mySrc[8], myW[8];
    int myDl[8];
    #pragma unroll
    for (int k = 0; k < 8; ++k) {
        int i = base + t * 8 + k;
        if (i < e) {
            int d = dst[i];
            myB[k] = d >> BSH;
            myDl[k] = d & 511;
            mySrc[k] = (unsigned int)src[i];
            myW[k] = __float_as_uint(w[i]);
            myR[k] = atomicAdd(&cnt[myB[k]], 1);
        } else {
            myB[k] = -1;
        }
    }
    __syncthreads();
    int c = cnt[t];
    s[t] = c;
    __syncthreads();
    for (int off = 1; off < 256; off <<= 1) {
        int u = (t >= off) ? s[t - off] : 0;
        __syncthreads();
        s[t] += u;
        __syncthreads();
    }
    lscan[t] = s[t] - c;
    if (c > 0) gbase[t] = atomicAdd(&bucketCursor[t], c);
    __syncthreads();
    #pragma unroll
    for (int k = 0; k < 8; ++k) {
        if (myB[k] >= 0) {
            int lpos = lscan[myB[k]] + myR[k];
            rec[lpos] = make_uint2(mySrc[k] | ((unsigned int)myDl[k] << 17), myW[k]);
            bof[lpos] = (unsigned short)myB[k];
        }
    }
    __syncthreads();
    int m = e - base; if (m > 2048) m = 2048;
    for (int i = t; i < m; i += 256) {
        int b = bof[i];
        etmp[gbase[b] + (i - lscan[b])] = rec[i];
    }
}

// pass 3: per-bucket local CSR + degree -> dinv. One block per bucket (512 nodes).
__global__ void k_pass3(const uint2* __restrict__ etmp, const int* __restrict__ bucketBase,
                        int* __restrict__ R, uint2* __restrict__ epair,
                        float* __restrict__ dinv, int n) {
    __shared__ int hist[512];
    __shared__ float degs[512];
    __shared__ int s[256];
    int b = blockIdx.x, t = threadIdx.x;
    int lo = bucketBase[b], hi = bucketBase[b + 1];
    hist[t] = 0; hist[t + 256] = 0;
    degs[t] = 0.f; degs[t + 256] = 0.f;
    __syncthreads();
    for (int i = lo + t; i < hi; i += 256)
        atomicAdd(&hist[etmp[i].x >> 17], 1);
    __syncthreads();
    int c0 = hist[2 * t], c1 = hist[2 * t + 1];
    int p = c0 + c1;
    s[t] = p;
    __syncthreads();
    for (int off = 1; off < 256; off <<= 1) {
        int u = (t >= off) ? s[t - off] : 0;
        __syncthreads();
        s[t] += u;
        __syncthreads();
    }
    int excl = s[t] - p;
    int node0 = b << BSH;
    int e0 = excl, e1 = excl + c0;
    if (node0 + 2 * t < n)     R[node0 + 2 * t]     = lo + e0;
    if (node0 + 2 * t + 1 < n) R[node0 + 2 * t + 1] = lo + e1;
    __syncthreads();
    hist[2 * t] = e0; hist[2 * t + 1] = e1;   // cursors
    __syncthreads();
    for (int i = lo + t; i < hi; i += 256) {
        uint2 r = etmp[i];
        int dl = r.x >> 17;
        int slot = lo + atomicAdd(&hist[dl], 1);
        epair[slot] = make_uint2(r.x & 0x1FFFFu, r.y);
        atomicAdd(&degs[dl], __uint_as_float(r.y));
    }
    __syncthreads();
    for (int l = t; l < 512; l += 256) {
        int node = node0 + l;
        if (node < n) dinv[node] = rsqrtf(1.f + degs[l]);
    }
}

// ====== layer 0 fused: aggregate x (bf16, 16 feats) -> GEMM 16->128 + b0 -> Bbf ======
__global__ void k_layer0(const unsigned int* __restrict__ xbf, const uint2* __restrict__ epair,
                         const int* __restrict__ R, const float* __restrict__ dinv,
                         const float* __restrict__ W0, const float* __restrict__ b0,
                         unsigned int* __restrict__ Bbf, int n, int e) {
    __shared__ float Ws[16 * 128];
    __shared__ float xs[16 * 16];
    int tid = threadIdx.x;   // 128
    #pragma unroll
    for (int k = 0; k < 16; ++k) Ws[k * 128 + tid] = W0[k * 128 + tid];
    int node0 = blockIdx.x * 16;
    int node_l = tid >> 3, u = tid & 7;
    int node = node0 + node_l;
    if (node < n) {
        int start = R[node];
        int end = (node + 1 < n) ? R[node + 1] : e;
        float ax = 0.f, ay = 0.f;
        int j = start;
        for (; j + 3 < end; j += 4) {
            uint2 p0 = epair[j], p1 = epair[j + 1], p2 = epair[j + 2], p3 = epair[j + 3];
            float w0 = dinv[p0.x] * __uint_as_float(p0.y);
            float w1 = dinv[p1.x] * __uint_as_float(p1.y);
            float w2 = dinv[p2.x] * __uint_as_float(p2.y);
            float w3 = dinv[p3.x] * __uint_as_float(p3.y);
            unsigned int q0 = xbf[(size_t)p0.x * 8 + u];
            unsigned int q1 = xbf[(size_t)p1.x * 8 + u];
            unsigned int q2 = xbf[(size_t)p2.x * 8 + u];
            unsigned int q3 = xbf[(size_t)p3.x * 8 + u];
            ax += bflo(q0) * w0 + bflo(q1) * w1 + bflo(q2) * w2 + bflo(q3) * w3;
            ay += bfhi(q0) * w0 + bfhi(q1) * w1 + bfhi(q2) * w2 + bfhi(q3) * w3;
        }
        for (; j < end; ++j) {
            uint2 p0 = epair[j];
            float w0 = dinv[p0.x] * __uint_as_float(p0.y);
            unsigned int q0 = xbf[(size_t)p0.x * 8 + u];
            ax += bflo(q0) * w0;
            ay += bfhi(q0) * w0;
        }
        float di = dinv[node];
        unsigned int ps = xbf[(size_t)node * 8 + u];
        xs[node_l * 16 + 2 * u]     = ax * di + bflo(ps) * di * di;
        xs[node_l * 16 + 2 * u + 1] = ay * di + bfhi(ps) * di * di;
    }
    __syncthreads();
    int nrows = n - node0; if (nrows > 16) nrows = 16;
    float bf = b0[tid];
    for (int nl = 0; nl < nrows; ++nl) {
        float acc = bf;
        #pragma unroll
        for (int k = 0; k < 16; ++k) acc += xs[nl * 16 + k] * Ws[k * 128 + tid];
        float hi = __shfl_xor(acc, 1);
        if ((tid & 1) == 0)
            Bbf[(size_t)(node0 + nl) * 64 + (tid >> 1)] = packbf(acc, hi);
    }
}

// BN stats over packed bf16 rows
__global__ void k_bn_stats(const unsigned int* __restrict__ h, float* __restrict__ sums,
                           float* __restrict__ sumsq, int n) {
    int u = threadIdx.x & 63, half = threadIdx.x >> 6;   // blockDim 128
    int i0 = blockIdx.x * 256 + half;
    int i1 = blockIdx.x * 256 + 256; if (i1 > n) i1 = n;
    float sl = 0.f, shh = 0.f, ql = 0.f, qh = 0.f;
    for (int i = i0; i < i1; i += 2) {
        unsigned int p = h[(size_t)i * 64 + u];
        float lo = bflo(p), hi = bfhi(p);
        sl += lo; ql += lo * lo;
        shh += hi; qh += hi * hi;
    }
    atomicAdd(&sums[2 * u], sl);
    atomicAdd(&sums[2 * u + 1], shh);
    atomicAdd(&sumsq[2 * u], ql);
    atomicAdd(&sumsq[2 * u + 1], qh);
}

// BN0+ReLU fused on load (bf16 in); MFMA bf16 -> Abf bf16 packed (8 col-tiles).
__global__ __launch_bounds__(256) void k_gemm_hid_mfma(
        const uint4* __restrict__ Bbf4, const float* __restrict__ sums,
        const float* __restrict__ sumsq, const float* __restrict__ g,
        const float* __restrict__ be, const unsigned int* __restrict__ W1p,
        unsigned int* __restrict__ Abf, int n, float invn) {
    __shared__ __align__(16) unsigned int hsbf[64 * HSTRIDE];
    __shared__ float sc[128], sh[128];
    int tid = threadIdx.x;
    if (tid < 128) {
        float m = sums[tid] * invn;
        float v = sumsq[tid] * invn - m * m;
        float scale = rsqrtf(v + EPS_BN) * g[tid];
        sc[tid] = scale;
        sh[tid] = be[tid] - m * scale;
    }
    __syncthreads();
    int node0 = blockIdx.x * 64;
    for (int i = tid; i < 64 * 16; i += 256) {
        int row = i >> 4, q = i & 15;
        int gn = node0 + row;
        uint4 pk;
        if (gn < n) {
            uint4 p = Bbf4[(size_t)gn * 16 + q];
            int fb = q * 8;
            float v0 = fmaxf(bflo(p.x) * sc[fb + 0] + sh[fb + 0], 0.f);
            float v1 = fmaxf(bfhi(p.x) * sc[fb + 1] + sh[fb + 1], 0.f);
            float v2 = fmaxf(bflo(p.y) * sc[fb + 2] + sh[fb + 2], 0.f);
            float v3 = fmaxf(bfhi(p.y) * sc[fb + 3] + sh[fb + 3], 0.f);
            float v4 = fmaxf(bflo(p.z) * sc[fb + 4] + sh[fb + 4], 0.f);
            float v5 = fmaxf(bfhi(p.z) * sc[fb + 5] + sh[fb + 5], 0.f);
            float v6 = fmaxf(bflo(p.w) * sc[fb + 6] + sh[fb + 6], 0.f);
            float v7 = fmaxf(bfhi(p.w) * sc[fb + 7] + sh[fb + 7], 0.f);
            pk = make_uint4(packbf(v0, v1), packbf(v2, v3), packbf(v4, v5), packbf(v6, v7));
        } else {
            pk = make_uint4(0u, 0u, 0u, 0u);
        }
        *((uint4*)&hsbf[row * HSTRIDE + q * 4]) = pk;
    }
    __syncthreads();
    int wave = tid >> 6, lane = tid & 63;
    int quad = lane >> 4, mrow = lane & 15;
    int lrow = wave * 16 + mrow;
    s16x8 afrag[4];
    #pragma unroll
    for (int kc = 0; kc < 4; ++kc)
        afrag[kc] = *((const s16x8*)&hsbf[lrow * HSTRIDE + kc * 16 + quad * 4]);
    int gnode_base = node0 + wave * 16;
    const s16x8* Wf = (const s16x8*)W1p;
    for (int ct = 0; ct < 8; ++ct) {
        f32x4 acc = {0.f, 0.f, 0.f, 0.f};
        #pragma unroll
        for (int kc = 0; kc < 4; ++kc) {
            s16x8 bfrag = Wf[(ct * 4 + kc) * 64 + lane];
            acc = __builtin_amdgcn_mfma_f32_16x16x32_bf16(afrag[kc], bfrag, acc, 0, 0, 0);
        }
        #pragma unroll
        for (int r = 0; r < 4; ++r) {
            float lo = acc[r];
            float hi = __shfl_xor(lo, 1);
            int grow = gnode_base + quad * 4 + r;
            if ((mrow & 1) == 0 && grow < n)
                Abf[(size_t)grow * 64 + ct * 8 + (mrow >> 1)] = packbf(lo, hi);
        }
    }
}

// BN1+ReLU fused on load (bf16 in); MFMA (N,128)@W2(128,16-padded) -> A16bf stride-16 bf16
__global__ __launch_bounds__(256) void k_gemm_out_mfma(
        const uint4* __restrict__ Bbf4, const float* __restrict__ sums,
        const float* __restrict__ sumsq, const float* __restrict__ g,
        const float* __restrict__ be, const unsigned int* __restrict__ W2p,
        unsigned int* __restrict__ A16bf, int n, float invn) {
    __shared__ __align__(16) unsigned int hsbf[64 * HSTRIDE];
    __shared__ float sc[128], sh[128];
    int tid = threadIdx.x;
    if (tid < 128) {
        float m = sums[tid] * invn;
        float v = sumsq[tid] * invn - m * m;
        float scale = rsqrtf(v + EPS_BN) * g[tid];
        sc[tid] = scale;
        sh[tid] = be[tid] - m * scale;
    }
    __syncthreads();
    int node0 = blockIdx.x * 64;
    for (int i = tid; i < 64 * 16; i += 256) {
        int row = i >> 4, q = i & 15;
        int gn = node0 + row;
        uint4 pk;
        if (gn < n) {
            uint4 p = Bbf4[(size_t)gn * 16 + q];
            int fb = q * 8;
            float v0 = fmaxf(bflo(p.x) * sc[fb + 0] + sh[fb + 0], 0.f);
            float v1 = fmaxf(bfhi(p.x) * sc[fb + 1] + sh[fb + 1], 0.f);
            float v2 = fmaxf(bflo(p.y) * sc[fb + 2] + sh[fb + 2], 0.f);
            float v3 = fmaxf(bfhi(p.y) * sc[fb + 3] + sh[fb + 3], 0.f);
            float v4 = fmaxf(bflo(p.z) * sc[fb + 4] + sh[fb + 4], 0.f);
            float v5 = fmaxf(bfhi(p.z) * sc[fb + 5] + sh[fb + 5], 0.f);
            float v6 = fmaxf(bflo(p.w) * sc[fb + 6] + sh[fb + 6], 0.f);
            float v7 = fmaxf(bfhi(p.w) * sc[fb + 7] + sh[fb + 7], 0.f);
            pk = make_uint4(packbf(v0, v1), packbf(v2, v3), packbf(v4, v5), packbf(v6, v7));
        } else {
            pk = make_uint4(0u, 0u, 0u, 0u);
        }
        *((uint4*)&hsbf[row * HSTRIDE + q * 4]) = pk;
    }
    __syncthreads();
    int wave = tid >> 6, lane = tid & 63;
    int quad = lane >> 4, mrow = lane & 15;
    int lrow = wave * 16 + mrow;
    s16x8 afrag[4];
    #pragma unroll
    for (int kc = 0; kc < 4; ++kc)
        afrag[kc] = *((const s16x8*)&hsbf[lrow * HSTRIDE + kc * 16 + quad * 4]);
    int gnode_base = node0 + wave * 16;
    const s16x8* Wf = (const s16x8*)W2p;
    f32x4 acc = {0.f, 0.f, 0.f, 0.f};
    #pragma unroll
    for (int kc = 0; kc < 4; ++kc) {
        s16x8 bfrag = Wf[kc * 64 + lane];
        acc = __builtin_amdgcn_mfma_f32_16x16x32_bf16(afrag[kc], bfrag, acc, 0, 0, 0);
    }
    #pragma unroll
    for (int r = 0; r < 4; ++r) {
        float lo = acc[r];
        float hi = __shfl_xor(lo, 1);
        int grow = gnode_base + quad * 4 + r;
        if ((mrow & 1) == 0 && grow < n)
            A16bf[(size_t)grow * 8 + (mrow >> 1)] = packbf(lo, hi);
    }
}

// layer-1: 128-feature bf16 aggregation. wave/node, four 16-lane groups.
__global__ void k_aggregate128(const uint4* __restrict__ Abf4, const uint2* __restrict__ epair,
                               const int* __restrict__ R, const float* __restrict__ dinv,
                               const float4* __restrict__ bias4, uint4* __restrict__ Bbf4,
                               int n, int e) {
    int gid = blockIdx.x * blockDim.x + threadIdx.x;
    int node = gid >> 6;
    if (node >= n) return;
    int lane = threadIdx.x & 63;
    int grp = lane >> 4, sub = lane & 15;
    int start = R[node];
    int end = (node + 1 < n) ? R[node + 1] : e;
    float a[8] = {0.f, 0.f, 0.f, 0.f, 0.f, 0.f, 0.f, 0.f};
    for (int base = start; base < end; base += 64) {
        int m = end - base; if (m > 64) m = 64;
        int myS = 0; float myW = 0.f;
        if (lane < m) {
            uint2 pr = epair[base + lane];
            myS = (int)pr.x;
            myW = dinv[pr.x] * __uint_as_float(pr.y);
        }
        for (int t = 0; t < m; t += 16) {
            int j0 = t + grp, j1 = t + 4 + grp, j2 = t + 8 + grp, j3 = t + 12 + grp;
            int s0 = __shfl(myS, j0); float w0 = __shfl(myW, j0);
            int s1 = __shfl(myS, j1); float w1 = __shfl(myW, j1);
            int s2 = __shfl(myS, j2); float w2 = __shfl(myW, j2);
            int s3 = __shfl(myS, j3); float w3 = __shfl(myW, j3);
            if (j0 < m) {
                uint4 p = Abf4[(size_t)s0 * 16 + sub];
                a[0] += bflo(p.x) * w0; a[1] += bfhi(p.x) * w0;
                a[2] += bflo(p.y) * w0; a[3] += bfhi(p.y) * w0;
                a[4] += bflo(p.z) * w0; a[5] += bfhi(p.z) * w0;
                a[6] += bflo(p.w) * w0; a[7] += bfhi(p.w) * w0;
            }
            if (j1 < m) {
                uint4 p = Abf4[(size_t)s1 * 16 + sub];
                a[0] += bflo(p.x) * w1; a[1] += bfhi(p.x) * w1;
                a[2] += bflo(p.y) * w1; a[3] += bfhi(p.y) * w1;
                a[4] += bflo(p.z) * w1; a[5] += bfhi(p.z) * w1;
                a[6] += bflo(p.w) * w1; a[7] += bfhi(p.w) * w1;
            }
            if (j2 < m) {
                uint4 p = Abf4[(size_t)s2 * 16 + sub];
                a[0] += bflo(p.x) * w2; a[1] += bfhi(p.x) * w2;
                a[2] += bflo(p.y) * w2; a[3] += bfhi(p.y) * w2;
                a[4] += bflo(p.z) * w2; a[5] += bfhi(p.z) * w2;
                a[6] += bflo(p.w) * w2; a[7] += bfhi(p.w) * w2;
            }
            if (j3 < m) {
                uint4 p = Abf4[(size_t)s3 * 16 + sub];
                a[0] += bflo(p.x) * w3; a[1] += bfhi(p.x) * w3;
                a[2] += bflo(p.y) * w3; a[3] += bfhi(p.y) * w3;
                a[4] += bflo(p.z) * w3; a[5] += bfhi(p.z) * w3;
                a[6] += bflo(p.w) * w3; a[7] += bfhi(p.w) * w3;
            }
        }
    }
    #pragma unroll
    for (int k = 0; k < 8; ++k) {
        a[k] += __shfl_xor(a[k], 16);
        a[k] += __shfl_xor(a[k], 32);
    }
    if (grp == 0) {
        float di = dinv[node];
        uint4 ps = Abf4[(size_t)node * 16 + sub];
        float4 bl = bias4[2 * sub], bh = bias4[2 * sub + 1];
        float r0 = a[0] * di + bflo(ps.x) * di * di + bl.x;
        float r1 = a[1] * di + bfhi(ps.x) * di * di + bl.y;
        float r2 = a[2] * di + bflo(ps.y) * di * di + bl.z;
        float r3 = a[3] * di + bfhi(ps.y) * di * di + bl.w;
        float r4 = a[4] * di + bflo(ps.z) * di * di + bh.x;
        float r5 = a[5] * di + bfhi(ps.z) * di * di + bh.y;
        float r6 = a[6] * di + bflo(ps.w) * di * di + bh.z;
        float r7 = a[7] * di + bfhi(ps.w) * di * di + bh.w;
        Bbf4[(size_t)node * 16 + sub] = make_uint4(packbf(r0, r1), packbf(r2, r3),
                                                   packbf(r4, r5), packbf(r6, r7));
    }
}

// layer-2: 12-feature aggregation over bf16 stride-16 rows, unroll 4.
__global__ void k_agg_out(const unsigned int* __restrict__ A16bf, const uint2* __restrict__ epair,
                          const int* __restrict__ R, const float* __restrict__ dinv,
                          const float* __restrict__ b2, float* __restrict__ out, int n, int e) {
    int t = blockIdx.x * blockDim.x + threadIdx.x;
    int node = t >> 3, u = t & 7;
    if (node >= n || u >= 6) return;
    int start = R[node];
    int end = (node + 1 < n) ? R[node + 1] : e;
    float ax = 0.f, ay = 0.f;
    int j = start;
    for (; j + 3 < end; j += 4) {
        uint2 p0 = epair[j], p1 = epair[j + 1], p2 = epair[j + 2], p3 = epair[j + 3];
        float w0 = dinv[p0.x] * __uint_as_float(p0.y);
        float w1 = dinv[p1.x] * __uint_as_float(p1.y);
        float w2 = dinv[p2.x] * __uint_as_float(p2.y);
        float w3 = dinv[p3.x] * __uint_as_float(p3.y);
        unsigned int q0 = A16bf[(size_t)p0.x * 8 + u];
        unsigned int q1 = A16bf[(size_t)p1.x * 8 + u];
        unsigned int q2 = A16bf[(size_t)p2.x * 8 + u];
        unsigned int q3 = A16bf[(size_t)p3.x * 8 + u];
        ax += bflo(q0) * w0 + bflo(q1) * w1 + bflo(q2) * w2 + bflo(q3) * w3;
        ay += bfhi(q0) * w0 + bfhi(q1) * w1 + bfhi(q2) * w2 + bfhi(q3) * w3;
    }
    for (; j < end; ++j) {
        uint2 p0 = epair[j];
        float w0 = dinv[p0.x] * __uint_as_float(p0.y);
        unsigned int q0 = A16bf[(size_t)p0.x * 8 + u];
        ax += bflo(q0) * w0;
        ay += bfhi(q0) * w0;
    }
    float di = dinv[node];
    unsigned int ps = A16bf[(size_t)node * 8 + u];
    ax = ax * di + bflo(ps) * di * di + b2[2 * u];
    ay = ay * di + bfhi(ps) * di * di + b2[2 * u + 1];
    ((float2*)(out + (size_t)node * 12))[u] = make_float2(ax, ay);
}

// ================= launch =================
extern "C" void kernel_launch(void* const* d_in, const int* in_sizes, int n_in,
                              void* d_out, int out_size, void* d_ws, size_t ws_size,
                              hipStream_t stream) {
    const float* x   = (const float*)d_in[0];
    const int*   ei  = (const int*)d_in[1];
    const float* ew  = (const float*)d_in[2];
    const float* W0  = (const float*)d_in[3];
    const float* b0  = (const float*)d_in[4];
    const float* W1  = (const float*)d_in[5];
    const float* b1  = (const float*)d_in[6];
    const float* W2  = (const float*)d_in[7];
    const float* b2  = (const float*)d_in[8];
    const float* g0  = (const float*)d_in[9];
    const float* be0 = (const float*)d_in[10];
    const float* g1  = (const float*)d_in[11];
    const float* be1 = (const float*)d_in[12];
    float* out = (float*)d_out;

    const int n = in_sizes[0] / 16;   // 100000
    const int e = in_sizes[2];        // 1600000
    const int* src = ei;
    const int* dst = ei + e;
    const int NB = (n + 511) >> 9;                 // 196 buckets
    const int NHIST = (e + 4095) / 4096;           // 391 histogram blocks

    // workspace layout (4B elems); etmp aliases B region; bHist aliases Abf region
    float*        wsf   = (float*)d_ws;
    float*        dinv  = wsf;                                    // n
    int*          R     = (int*)(wsf + n);                        // n+4
    int*          bBase = R + (n + 4);                            // 520
    int*          bCur  = bBase + 520;                            // 512
    uint2*        epair = (uint2*)(bCur + 512);                   // e pairs
    float*        B     = (float*)(bCur + 512 + 2 * (size_t)e);   // region (n*128 dwords)
    uint2*        etmp  = (uint2*)B;                              // e pairs, aliases B
    unsigned int* Bbf   = (unsigned int*)B;                       // n*64 (bf16 packed)
    unsigned int* Abf   = (unsigned int*)(B + (size_t)n * 128);   // n*64
    int*          bHist = (int*)Abf;                              // NHIST*256 ints, aliases Abf
    unsigned int* xbf   = Abf + (size_t)n * 64;                   // n*8
    unsigned int* A16bf = xbf + (size_t)n * 8;                    // n*8
    float*        stat0 = (float*)(A16bf + (size_t)n * 8);        // 256
    float*        stat1 = stat0 + 256;                            // 256
    unsigned int* W1p   = (unsigned int*)(stat1 + 256);           // 8192
    unsigned int* W2p   = W1p + 8192;                             // 1024

    const float invn = 1.0f / (float)n;

    // ---- build + prep (11 dispatches total, no memset, no global hist atomics) ----
    k_prep_all<<<(n * 8 + 255) / 256, 256, 0, stream>>>(x, xbf, n * 8, W1, W1p, W2, W2p,
                                                        dst, bHist, e, NHIST);
    k_reduce_scan<<<1, 256, 0, stream>>>(bHist, bBase, bCur, NB, e, NHIST, stat0, stat1);
    k_pass2<<<(e + 2047) / 2048, 256, 0, stream>>>(src, dst, ew, bCur, etmp, e);
    k_pass3<<<NB, 256, 0, stream>>>(etmp, bBase, R, epair, dinv, n);

    // ---- layer 0 (fused aggregate + 16->128 GEMM + bias) ----
    k_layer0<<<(n + 15) / 16, 128, 0, stream>>>(xbf, epair, R, dinv, W0, b0, Bbf, n, e);
    k_bn_stats<<<(n + 255) / 256, 128, 0, stream>>>(Bbf, stat0, stat0 + 128, n);

    // ---- layer 1 (MFMA GEMM with fused BN0+ReLU, then aggregation) ----
    k_gemm_hid_mfma<<<(n + 63) / 64, 256, 0, stream>>>((const uint4*)Bbf, stat0, stat0 + 128,
                                                       g0, be0, W1p, Abf, n, invn);
    k_aggregate128<<<(n * 64 + 255) / 256, 256, 0, stream>>>((const uint4*)Abf, epair, R, dinv,
                                                             (const float4*)b1, (uint4*)Bbf, n, e);
    k_bn_stats<<<(n + 255) / 256, 128, 0, stream>>>(Bbf, stat1, stat1 + 128, n);

    // ---- layer 2 (MFMA GEMM with fused BN1+ReLU, then aggregation to out) ----
    k_gemm_out_mfma<<<(n + 63) / 64, 256, 0, stream>>>((const uint4*)Bbf, stat1, stat1 + 128,
                                                       g1, be1, W2p, A16bf, n, invn);
    k_agg_out<<<(n * 8 + 255) / 256, 256, 0, stream>>>(A16bf, epair, R, dinv, b2, out, n, e);
}

// Round 14
// 502.466 us; speedup vs baseline: 1.8822x; 1.0830x over previous
//
#include <hip/hip_runtime.h>

#define EPS_BN 1e-5f
#define HSTRIDE 68   // 64 dwords + 4 pad (272B rows, 16B-aligned)
#define BSH 9        // bucket = 512 consecutive nodes

typedef __attribute__((ext_vector_type(4))) float f32x4;
typedef __attribute__((ext_vector_type(8))) short s16x8;

__device__ inline unsigned short f2bf(float f) {
    unsigned int u = __float_as_uint(f);
    unsigned int r = (u + 0x7fffu + ((u >> 16) & 1u)) >> 16;
    return (unsigned short)r;
}
__device__ inline unsigned int packbf(float lo, float hi) {
    return (unsigned int)f2bf(lo) | ((unsigned int)f2bf(hi) << 16);
}
__device__ inline float bflo(unsigned int p) { return __uint_as_float(p << 16); }
__device__ inline float bfhi(unsigned int p) { return __uint_as_float(p & 0xffff0000u); }

// ====== combined prep: x->bf16, W1/W2 -> MFMA B-frags, bucket histogram ======
__global__ void k_prep_all(const float* __restrict__ x, unsigned int* __restrict__ xbf, int n8,
                           const float* __restrict__ W1, unsigned int* __restrict__ W1p,
                           const float* __restrict__ W2, unsigned int* __restrict__ W2p,
                           const int* __restrict__ dst, int* __restrict__ bCnt,
                           int e, int nhist) {
    __shared__ int cnt[256];
    int tid = threadIdx.x;
    bool hb = ((int)blockIdx.x < nhist);
    if (hb) cnt[tid] = 0;
    __syncthreads();
    int t = blockIdx.x * 256 + tid;
    if (t < n8) {
        float2 v = ((const float2*)x)[t];
        xbf[t] = packbf(v.x, v.y);
    }
    if (t < 8192) {
        int dj = t & 3;
        int lane = (t >> 2) & 63;
        int kc = (t >> 8) & 3;
        int ct = t >> 10;
        int quad = lane >> 4, mrow = lane & 15;
        int k0 = kc * 32 + quad * 8 + dj * 2;
        int col = ct * 16 + mrow;
        W1p[t] = packbf(W1[k0 * 128 + col], W1[(k0 + 1) * 128 + col]);
    }
    if (t < 1024) {
        int dj = t & 3;
        int lane = (t >> 2) & 63;
        int kc = t >> 8;                   // 0..3
        int quad = lane >> 4, mrow = lane & 15;
        int k0 = kc * 32 + quad * 8 + dj * 2;
        float lo = (mrow < 12) ? W2[k0 * 12 + mrow] : 0.f;
        float hi = (mrow < 12) ? W2[(k0 + 1) * 12 + mrow] : 0.f;
        W2p[t] = packbf(lo, hi);
    }
    if (hb) {
        int base = blockIdx.x * 4096 + tid * 16;
        #pragma unroll
        for (int k = 0; k < 16; ++k) {
            int i = base + k;
            if (i < e) atomicAdd(&cnt[dst[i] >> BSH], 1);
        }
    }
    __syncthreads();
    if (hb) {
        int c = cnt[tid];
        if (c) atomicAdd(&bCnt[tid], c);
    }
}

// exclusive scan of bucket counts -> bucketBase, init cursors; zero BN stat buffers
__global__ void k_scan_buckets(const int* __restrict__ bucketCnt, int* __restrict__ bucketBase,
                               int* __restrict__ bucketCursor, int nb, int e,
                               float* __restrict__ stat0, float* __restrict__ stat1) {
    __shared__ int s[256];
    int t = threadIdx.x;
    stat0[t] = 0.f;
    stat1[t] = 0.f;
    int v = (t < nb) ? bucketCnt[t] : 0;
    s[t] = v;
    __syncthreads();
    for (int off = 1; off < 256; off <<= 1) {
        int u = (t >= off) ? s[t - off] : 0;
        __syncthreads();
        s[t] += u;
        __syncthreads();
    }
    int excl = s[t] - v;
    if (t < nb) { bucketBase[t] = excl; bucketCursor[t] = excl; }
    if (t == 0) bucketBase[nb] = e;
}

// pass 2: scatter edges into bucket-partitioned etmp, coalesced via LDS staging.
__global__ void k_pass2(const int* __restrict__ src, const int* __restrict__ dst,
                        const float* __restrict__ w, int* __restrict__ bucketCursor,
                        uint2* __restrict__ etmp, int e) {
    __shared__ int cnt[256];
    __shared__ int s[256];
    __shared__ int gbase[256];
    __shared__ int lscan[256];
    __shared__ uint2 rec[2048];
    __shared__ unsigned short bof[2048];
    int t = threadIdx.x;
    cnt[t] = 0;
    __syncthreads();
    int base = blockIdx.x * 2048;
    int myB[8], myR[8];
    unsigned int mySrc[8], myW[8];
    int myDl[8];
    #pragma unroll
    for (int k = 0; k < 8; ++k) {
        int i = base + t * 8 + k;
        if (i < e) {
            int d = dst[i];
            myB[k] = d >> BSH;
            myDl[k] = d & 511;
            mySrc[k] = (unsigned int)src[i];
            myW[k] = __float_as_uint(w[i]);
            myR[k] = atomicAdd(&cnt[myB[k]], 1);
        } else {
            myB[k] = -1;
        }
    }
    __syncthreads();
    int c = cnt[t];
    s[t] = c;
    __syncthreads();
    for (int off = 1; off < 256; off <<= 1) {
        int u = (t >= off) ? s[t - off] : 0;
        __syncthreads();
        s[t] += u;
        __syncthreads();
    }
    lscan[t] = s[t] - c;
    if (c > 0) gbase[t] = atomicAdd(&bucketCursor[t], c);
    __syncthreads();
    #pragma unroll
    for (int k = 0; k < 8; ++k) {
        if (myB[k] >= 0) {
            int lpos = lscan[myB[k]] + myR[k];
            rec[lpos] = make_uint2(mySrc[k] | ((unsigned int)myDl[k] << 17), myW[k]);
            bof[lpos] = (unsigned short)myB[k];
        }
    }
    __syncthreads();
    int m = e - base; if (m > 2048) m = 2048;
    for (int i = t; i < m; i += 256) {
        int b = bof[i];
        etmp[gbase[b] + (i - lscan[b])] = rec[i];
    }
}

// pass 3: per-bucket local CSR + degree -> dinv. One block per bucket (512 nodes).
__global__ void k_pass3(const uint2* __restrict__ etmp, const int* __restrict__ bucketBase,
                        int* __restrict__ R, uint2* __restrict__ epair,
                        float* __restrict__ dinv, int n) {
    __shared__ int hist[512];
    __shared__ float degs[512];
    __shared__ int s[256];
    int b = blockIdx.x, t = threadIdx.x;
    int lo = bucketBase[b], hi = bucketBase[b + 1];
    hist[t] = 0; hist[t + 256] = 0;
    degs[t] = 0.f; degs[t + 256] = 0.f;
    __syncthreads();
    for (int i = lo + t; i < hi; i += 256)
        atomicAdd(&hist[etmp[i].x >> 17], 1);
    __syncthreads();
    int c0 = hist[2 * t], c1 = hist[2 * t + 1];
    int p = c0 + c1;
    s[t] = p;
    __syncthreads();
    for (int off = 1; off < 256; off <<= 1) {
        int u = (t >= off) ? s[t - off] : 0;
        __syncthreads();
        s[t] += u;
        __syncthreads();
    }
    int excl = s[t] - p;
    int node0 = b << BSH;
    int e0 = excl, e1 = excl + c0;
    if (node0 + 2 * t < n)     R[node0 + 2 * t]     = lo + e0;
    if (node0 + 2 * t + 1 < n) R[node0 + 2 * t + 1] = lo + e1;
    __syncthreads();
    hist[2 * t] = e0; hist[2 * t + 1] = e1;   // cursors
    __syncthreads();
    for (int i = lo + t; i < hi; i += 256) {
        uint2 r = etmp[i];
        int dl = r.x >> 17;
        int slot = lo + atomicAdd(&hist[dl], 1);
        epair[slot] = make_uint2(r.x & 0x1FFFFu, r.y);
        atomicAdd(&degs[dl], __uint_as_float(r.y));
    }
    __syncthreads();
    for (int l = t; l < 512; l += 256) {
        int node = node0 + l;
        if (node < n) dinv[node] = rsqrtf(1.f + degs[l]);
    }
}

// ====== layer 0 fused: aggregate x (bf16, 16 feats) -> GEMM 16->128 + b0 -> Bbf ======
__global__ void k_layer0(const unsigned int* __restrict__ xbf, const uint2* __restrict__ epair,
                         const int* __restrict__ R, const float* __restrict__ dinv,
                         const float* __restrict__ W0, const float* __restrict__ b0,
                         unsigned int* __restrict__ Bbf, int n, int e) {
    __shared__ float Ws[16 * 128];
    __shared__ float xs[16 * 16];
    int tid = threadIdx.x;   // 128
    #pragma unroll
    for (int k = 0; k < 16; ++k) Ws[k * 128 + tid] = W0[k * 128 + tid];
    int node0 = blockIdx.x * 16;
    int node_l = tid >> 3, u = tid & 7;
    int node = node0 + node_l;
    if (node < n) {
        int start = R[node];
        int end = (node + 1 < n) ? R[node + 1] : e;
        float ax = 0.f, ay = 0.f;
        int j = start;
        for (; j + 3 < end; j += 4) {
            uint2 p0 = epair[j], p1 = epair[j + 1], p2 = epair[j + 2], p3 = epair[j + 3];
            float w0 = dinv[p0.x] * __uint_as_float(p0.y);
            float w1 = dinv[p1.x] * __uint_as_float(p1.y);
            float w2 = dinv[p2.x] * __uint_as_float(p2.y);
            float w3 = dinv[p3.x] * __uint_as_float(p3.y);
            unsigned int q0 = xbf[(size_t)p0.x * 8 + u];
            unsigned int q1 = xbf[(size_t)p1.x * 8 + u];
            unsigned int q2 = xbf[(size_t)p2.x * 8 + u];
            unsigned int q3 = xbf[(size_t)p3.x * 8 + u];
            ax += bflo(q0) * w0 + bflo(q1) * w1 + bflo(q2) * w2 + bflo(q3) * w3;
            ay += bfhi(q0) * w0 + bfhi(q1) * w1 + bfhi(q2) * w2 + bfhi(q3) * w3;
        }
        for (; j < end; ++j) {
            uint2 p0 = epair[j];
            float w0 = dinv[p0.x] * __uint_as_float(p0.y);
            unsigned int q0 = xbf[(size_t)p0.x * 8 + u];
            ax += bflo(q0) * w0;
            ay += bfhi(q0) * w0;
        }
        float di = dinv[node];
        unsigned int ps = xbf[(size_t)node * 8 + u];
        xs[node_l * 16 + 2 * u]     = ax * di + bflo(ps) * di * di;
        xs[node_l * 16 + 2 * u + 1] = ay * di + bfhi(ps) * di * di;
    }
    __syncthreads();
    int nrows = n - node0; if (nrows > 16) nrows = 16;
    float bf = b0[tid];
    for (int nl = 0; nl < nrows; ++nl) {
        float acc = bf;
        #pragma unroll
        for (int k = 0; k < 16; ++k) acc += xs[nl * 16 + k] * Ws[k * 128 + tid];
        float hi = __shfl_xor(acc, 1);
        if ((tid & 1) == 0)
            Bbf[(size_t)(node0 + nl) * 64 + (tid >> 1)] = packbf(acc, hi);
    }
}

// BN stats over packed bf16 rows
__global__ void k_bn_stats(const unsigned int* __restrict__ h, float* __restrict__ sums,
                           float* __restrict__ sumsq, int n) {
    int u = threadIdx.x & 63, half = threadIdx.x >> 6;   // blockDim 128
    int i0 = blockIdx.x * 256 + half;
    int i1 = blockIdx.x * 256 + 256; if (i1 > n) i1 = n;
    float sl = 0.f, shh = 0.f, ql = 0.f, qh = 0.f;
    for (int i = i0; i < i1; i += 2) {
        unsigned int p = h[(size_t)i * 64 + u];
        float lo = bflo(p), hi = bfhi(p);
        sl += lo; ql += lo * lo;
        shh += hi; qh += hi * hi;
    }
    atomicAdd(&sums[2 * u], sl);
    atomicAdd(&sums[2 * u + 1], shh);
    atomicAdd(&sumsq[2 * u], ql);
    atomicAdd(&sumsq[2 * u + 1], qh);
}

// BN0+ReLU fused on load (bf16 in); MFMA bf16 -> Abf bf16 packed (8 col-tiles).
__global__ __launch_bounds__(256) void k_gemm_hid_mfma(
        const uint4* __restrict__ Bbf4, const float* __restrict__ sums,
        const float* __restrict__ sumsq, const float* __restrict__ g,
        const float* __restrict__ be, const unsigned int* __restrict__ W1p,
        unsigned int* __restrict__ Abf, int n, float invn) {
    __shared__ __align__(16) unsigned int hsbf[64 * HSTRIDE];
    __shared__ float sc[128], sh[128];
    int tid = threadIdx.x;
    if (tid < 128) {
        float m = sums[tid] * invn;
        float v = sumsq[tid] * invn - m * m;
        float scale = rsqrtf(v + EPS_BN) * g[tid];
        sc[tid] = scale;
        sh[tid] = be[tid] - m * scale;
    }
    __syncthreads();
    int node0 = blockIdx.x * 64;
    for (int i = tid; i < 64 * 16; i += 256) {
        int row = i >> 4, q = i & 15;
        int gn = node0 + row;
        uint4 pk;
        if (gn < n) {
            uint4 p = Bbf4[(size_t)gn * 16 + q];
            int fb = q * 8;
            float v0 = fmaxf(bflo(p.x) * sc[fb + 0] + sh[fb + 0], 0.f);
            float v1 = fmaxf(bfhi(p.x) * sc[fb + 1] + sh[fb + 1], 0.f);
            float v2 = fmaxf(bflo(p.y) * sc[fb + 2] + sh[fb + 2], 0.f);
            float v3 = fmaxf(bfhi(p.y) * sc[fb + 3] + sh[fb + 3], 0.f);
            float v4 = fmaxf(bflo(p.z) * sc[fb + 4] + sh[fb + 4], 0.f);
            float v5 = fmaxf(bfhi(p.z) * sc[fb + 5] + sh[fb + 5], 0.f);
            float v6 = fmaxf(bflo(p.w) * sc[fb + 6] + sh[fb + 6], 0.f);
            float v7 = fmaxf(bfhi(p.w) * sc[fb + 7] + sh[fb + 7], 0.f);
            pk = make_uint4(packbf(v0, v1), packbf(v2, v3), packbf(v4, v5), packbf(v6, v7));
        } else {
            pk = make_uint4(0u, 0u, 0u, 0u);
        }
        *((uint4*)&hsbf[row * HSTRIDE + q * 4]) = pk;
    }
    __syncthreads();
    int wave = tid >> 6, lane = tid & 63;
    int quad = lane >> 4, mrow = lane & 15;
    int lrow = wave * 16 + mrow;
    s16x8 afrag[4];
    #pragma unroll
    for (int kc = 0; kc < 4; ++kc)
        afrag[kc] = *((const s16x8*)&hsbf[lrow * HSTRIDE + kc * 16 + quad * 4]);
    int gnode_base = node0 + wave * 16;
    const s16x8* Wf = (const s16x8*)W1p;
    for (int ct = 0; ct < 8; ++ct) {
        f32x4 acc = {0.f, 0.f, 0.f, 0.f};
        #pragma unroll
        for (int kc = 0; kc < 4; ++kc) {
            s16x8 bfrag = Wf[(ct * 4 + kc) * 64 + lane];
            acc = __builtin_amdgcn_mfma_f32_16x16x32_bf16(afrag[kc], bfrag, acc, 0, 0, 0);
        }
        #pragma unroll
        for (int r = 0; r < 4; ++r) {
            float lo = acc[r];
            float hi = __shfl_xor(lo, 1);
            int grow = gnode_base + quad * 4 + r;
            if ((mrow & 1) == 0 && grow < n)
                Abf[(size_t)grow * 64 + ct * 8 + (mrow >> 1)] = packbf(lo, hi);
        }
    }
}

// BN1+ReLU fused on load (bf16 in); MFMA (N,128)@W2(128,16-padded) -> A16bf stride-16 bf16
__global__ __launch_bounds__(256) void k_gemm_out_mfma(
        const uint4* __restrict__ Bbf4, const float* __restrict__ sums,
        const float* __restrict__ sumsq, const float* __restrict__ g,
        const float* __restrict__ be, const unsigned int* __restrict__ W2p,
        unsigned int* __restrict__ A16bf, int n, float invn) {
    __shared__ __align__(16) unsigned int hsbf[64 * HSTRIDE];
    __shared__ float sc[128], sh[128];
    int tid = threadIdx.x;
    if (tid < 128) {
        float m = sums[tid] * invn;
        float v = sumsq[tid] * invn - m * m;
        float scale = rsqrtf(v + EPS_BN) * g[tid];
        sc[tid] = scale;
        sh[tid] = be[tid] - m * scale;
    }
    __syncthreads();
    int node0 = blockIdx.x * 64;
    for (int i = tid; i < 64 * 16; i += 256) {
        int row = i >> 4, q = i & 15;
        int gn = node0 + row;
        uint4 pk;
        if (gn < n) {
            uint4 p = Bbf4[(size_t)gn * 16 + q];
            int fb = q * 8;
            float v0 = fmaxf(bflo(p.x) * sc[fb + 0] + sh[fb + 0], 0.f);
            float v1 = fmaxf(bfhi(p.x) * sc[fb + 1] + sh[fb + 1], 0.f);
            float v2 = fmaxf(bflo(p.y) * sc[fb + 2] + sh[fb + 2], 0.f);
            float v3 = fmaxf(bfhi(p.y) * sc[fb + 3] + sh[fb + 3], 0.f);
            float v4 = fmaxf(bflo(p.z) * sc[fb + 4] + sh[fb + 4], 0.f);
            float v5 = fmaxf(bfhi(p.z) * sc[fb + 5] + sh[fb + 5], 0.f);
            float v6 = fmaxf(bflo(p.w) * sc[fb + 6] + sh[fb + 6], 0.f);
            float v7 = fmaxf(bfhi(p.w) * sc[fb + 7] + sh[fb + 7], 0.f);
            pk = make_uint4(packbf(v0, v1), packbf(v2, v3), packbf(v4, v5), packbf(v6, v7));
        } else {
            pk = make_uint4(0u, 0u, 0u, 0u);
        }
        *((uint4*)&hsbf[row * HSTRIDE + q * 4]) = pk;
    }
    __syncthreads();
    int wave = tid >> 6, lane = tid & 63;
    int quad = lane >> 4, mrow = lane & 15;
    int lrow = wave * 16 + mrow;
    s16x8 afrag[4];
    #pragma unroll
    for (int kc = 0; kc < 4; ++kc)
        afrag[kc] = *((const s16x8*)&hsbf[lrow * HSTRIDE + kc * 16 + quad * 4]);
    int gnode_base = node0 + wave * 16;
    const s16x8* Wf = (const s16x8*)W2p;
    f32x4 acc = {0.f, 0.f, 0.f, 0.f};
    #pragma unroll
    for (int kc = 0; kc < 4; ++kc) {
        s16x8 bfrag = Wf[kc * 64 + lane];
        acc = __builtin_amdgcn_mfma_f32_16x16x32_bf16(afrag[kc], bfrag, acc, 0, 0, 0);
    }
    #pragma unroll
    for (int r = 0; r < 4; ++r) {
        float lo = acc[r];
        float hi = __shfl_xor(lo, 1);
        int grow = gnode_base + quad * 4 + r;
        if ((mrow & 1) == 0 && grow < n)
            A16bf[(size_t)grow * 8 + (mrow >> 1)] = packbf(lo, hi);
    }
}

// layer-1: 128-feature bf16 aggregation. wave/node, four 16-lane groups.
__global__ void k_aggregate128(const uint4* __restrict__ Abf4, const uint2* __restrict__ epair,
                               const int* __restrict__ R, const float* __restrict__ dinv,
                               const float4* __restrict__ bias4, uint4* __restrict__ Bbf4,
                               int n, int e) {
    int gid = blockIdx.x * blockDim.x + threadIdx.x;
    int node = gid >> 6;
    if (node >= n) return;
    int lane = threadIdx.x & 63;
    int grp = lane >> 4, sub = lane & 15;
    int start = R[node];
    int end = (node + 1 < n) ? R[node + 1] : e;
    float a[8] = {0.f, 0.f, 0.f, 0.f, 0.f, 0.f, 0.f, 0.f};
    for (int base = start; base < end; base += 64) {
        int m = end - base; if (m > 64) m = 64;
        int myS = 0; float myW = 0.f;
        if (lane < m) {
            uint2 pr = epair[base + lane];
            myS = (int)pr.x;
            myW = dinv[pr.x] * __uint_as_float(pr.y);
        }
        for (int t = 0; t < m; t += 16) {
            int j0 = t + grp, j1 = t + 4 + grp, j2 = t + 8 + grp, j3 = t + 12 + grp;
            int s0 = __shfl(myS, j0); float w0 = __shfl(myW, j0);
            int s1 = __shfl(myS, j1); float w1 = __shfl(myW, j1);
            int s2 = __shfl(myS, j2); float w2 = __shfl(myW, j2);
            int s3 = __shfl(myS, j3); float w3 = __shfl(myW, j3);
            if (j0 < m) {
                uint4 p = Abf4[(size_t)s0 * 16 + sub];
                a[0] += bflo(p.x) * w0; a[1] += bfhi(p.x) * w0;
                a[2] += bflo(p.y) * w0; a[3] += bfhi(p.y) * w0;
                a[4] += bflo(p.z) * w0; a[5] += bfhi(p.z) * w0;
                a[6] += bflo(p.w) * w0; a[7] += bfhi(p.w) * w0;
            }
            if (j1 < m) {
                uint4 p = Abf4[(size_t)s1 * 16 + sub];
                a[0] += bflo(p.x) * w1; a[1] += bfhi(p.x) * w1;
                a[2] += bflo(p.y) * w1; a[3] += bfhi(p.y) * w1;
                a[4] += bflo(p.z) * w1; a[5] += bfhi(p.z) * w1;
                a[6] += bflo(p.w) * w1; a[7] += bfhi(p.w) * w1;
            }
            if (j2 < m) {
                uint4 p = Abf4[(size_t)s2 * 16 + sub];
                a[0] += bflo(p.x) * w2; a[1] += bfhi(p.x) * w2;
                a[2] += bflo(p.y) * w2; a[3] += bfhi(p.y) * w2;
                a[4] += bflo(p.z) * w2; a[5] += bfhi(p.z) * w2;
                a[6] += bflo(p.w) * w2; a[7] += bfhi(p.w) * w2;
            }
            if (j3 < m) {
                uint4 p = Abf4[(size_t)s3 * 16 + sub];
                a[0] += bflo(p.x) * w3; a[1] += bfhi(p.x) * w3;
                a[2] += bflo(p.y) * w3; a[3] += bfhi(p.y) * w3;
                a[4] += bflo(p.z) * w3; a[5] += bfhi(p.z) * w3;
                a[6] += bflo(p.w) * w3; a[7] += bfhi(p.w) * w3;
            }
        }
    }
    #pragma unroll
    for (int k = 0; k < 8; ++k) {
        a[k] += __shfl_xor(a[k], 16);
        a[k] += __shfl_xor(a[k], 32);
    }
    if (grp == 0) {
        float di = dinv[node];
        uint4 ps = Abf4[(size_t)node * 16 + sub];
        float4 bl = bias4[2 * sub], bh = bias4[2 * sub + 1];
        float r0 = a[0] * di + bflo(ps.x) * di * di + bl.x;
        float r1 = a[1] * di + bfhi(ps.x) * di * di + bl.y;
        float r2 = a[2] * di + bflo(ps.y) * di * di + bl.z;
        float r3 = a[3] * di + bfhi(ps.y) * di * di + bl.w;
        float r4 = a[4] * di + bflo(ps.z) * di * di + bh.x;
        float r5 = a[5] * di + bfhi(ps.z) * di * di + bh.y;
        float r6 = a[6] * di + bflo(ps.w) * di * di + bh.z;
        float r7 = a[7] * di + bfhi(ps.w) * di * di + bh.w;
        Bbf4[(size_t)node * 16 + sub] = make_uint4(packbf(r0, r1), packbf(r2, r3),
                                                   packbf(r4, r5), packbf(r6, r7));
    }
}

// layer-2: 12-feature aggregation over bf16 stride-16 rows, unroll 4.
__global__ void k_agg_out(const unsigned int* __restrict__ A16bf, const uint2* __restrict__ epair,
                          const int* __restrict__ R, const float* __restrict__ dinv,
                          const float* __restrict__ b2, float* __restrict__ out, int n, int e) {
    int t = blockIdx.x * blockDim.x + threadIdx.x;
    int node = t >> 3, u = t & 7;
    if (node >= n || u >= 6) return;
    int start = R[node];
    int end = (node + 1 < n) ? R[node + 1] : e;
    float ax = 0.f, ay = 0.f;
    int j = start;
    for (; j + 3 < end; j += 4) {
        uint2 p0 = epair[j], p1 = epair[j + 1], p2 = epair[j + 2], p3 = epair[j + 3];
        float w0 = dinv[p0.x] * __uint_as_float(p0.y);
        float w1 = dinv[p1.x] * __uint_as_float(p1.y);
        float w2 = dinv[p2.x] * __uint_as_float(p2.y);
        float w3 = dinv[p3.x] * __uint_as_float(p3.y);
        unsigned int q0 = A16bf[(size_t)p0.x * 8 + u];
        unsigned int q1 = A16bf[(size_t)p1.x * 8 + u];
        unsigned int q2 = A16bf[(size_t)p2.x * 8 + u];
        unsigned int q3 = A16bf[(size_t)p3.x * 8 + u];
        ax += bflo(q0) * w0 + bflo(q1) * w1 + bflo(q2) * w2 + bflo(q3) * w3;
        ay += bfhi(q0) * w0 + bfhi(q1) * w1 + bfhi(q2) * w2 + bfhi(q3) * w3;
    }
    for (; j < end; ++j) {
        uint2 p0 = epair[j];
        float w0 = dinv[p0.x] * __uint_as_float(p0.y);
        unsigned int q0 = A16bf[(size_t)p0.x * 8 + u];
        ax += bflo(q0) * w0;
        ay += bfhi(q0) * w0;
    }
    float di = dinv[node];
    unsigned int ps = A16bf[(size_t)node * 8 + u];
    ax = ax * di + bflo(ps) * di * di + b2[2 * u];
    ay = ay * di + bfhi(ps) * di * di + b2[2 * u + 1];
    ((float2*)(out + (size_t)node * 12))[u] = make_float2(ax, ay);
}

// ================= launch =================
extern "C" void kernel_launch(void* const* d_in, const int* in_sizes, int n_in,
                              void* d_out, int out_size, void* d_ws, size_t ws_size,
                              hipStream_t stream) {
    const float* x   = (const float*)d_in[0];
    const int*   ei  = (const int*)d_in[1];
    const float* ew  = (const float*)d_in[2];
    const float* W0  = (const float*)d_in[3];
    const float* b0  = (const float*)d_in[4];
    const float* W1  = (const float*)d_in[5];
    const float* b1  = (const float*)d_in[6];
    const float* W2  = (const float*)d_in[7];
    const float* b2  = (const float*)d_in[8];
    const float* g0  = (const float*)d_in[9];
    const float* be0 = (const float*)d_in[10];
    const float* g1  = (const float*)d_in[11];
    const float* be1 = (const float*)d_in[12];
    float* out = (float*)d_out;

    const int n = in_sizes[0] / 16;   // 100000
    const int e = in_sizes[2];        // 1600000
    const int* src = ei;
    const int* dst = ei + e;
    const int NB = (n + 511) >> 9;                 // 196 buckets
    const int NHIST = (e + 4095) / 4096;           // 391 histogram blocks

    // workspace layout (4B elems); etmp aliases B region (dead before Bbf written)
    float*        wsf   = (float*)d_ws;
    float*        dinv  = wsf;                                    // n
    int*          R     = (int*)(wsf + n);                        // n+4
    int*          bCnt  = R + (n + 4);                            // 512
    int*          bBase = bCnt + 512;                             // 520
    int*          bCur  = bBase + 520;                            // 512
    uint2*        epair = (uint2*)(bCur + 512);                   // e pairs
    float*        B     = (float*)(bCur + 512 + 2 * (size_t)e);   // region (n*128 dwords)
    uint2*        etmp  = (uint2*)B;                              // e pairs, aliases B
    unsigned int* Bbf   = (unsigned int*)B;                       // n*64 (bf16 packed)
    unsigned int* Abf   = (unsigned int*)(B + (size_t)n * 128);   // n*64
    unsigned int* xbf   = Abf + (size_t)n * 64;                   // n*8
    unsigned int* A16bf = xbf + (size_t)n * 8;                    // n*8
    float*        stat0 = (float*)(A16bf + (size_t)n * 8);        // 256 (sums|sumsq)
    float*        stat1 = stat0 + 256;                            // 256
    unsigned int* W1p   = (unsigned int*)(stat1 + 256);           // 8192
    unsigned int* W2p   = W1p + 8192;                             // 1024

    const float invn = 1.0f / (float)n;

    // ---- build + prep ----
    hipMemsetAsync(bCnt, 0, 512 * sizeof(int), stream);
    k_prep_all<<<(n * 8 + 255) / 256, 256, 0, stream>>>(x, xbf, n * 8, W1, W1p, W2, W2p,
                                                        dst, bCnt, e, NHIST);
    k_scan_buckets<<<1, 256, 0, stream>>>(bCnt, bBase, bCur, NB, e, stat0, stat1);
    k_pass2<<<(e + 2047) / 2048, 256, 0, stream>>>(src, dst, ew, bCur, etmp, e);
    k_pass3<<<NB, 256, 0, stream>>>(etmp, bBase, R, epair, dinv, n);

    // ---- layer 0 (fused aggregate + 16->128 GEMM + bias) ----
    k_layer0<<<(n + 15) / 16, 128, 0, stream>>>(xbf, epair, R, dinv, W0, b0, Bbf, n, e);
    k_bn_stats<<<(n + 255) / 256, 128, 0, stream>>>(Bbf, stat0, stat0 + 128, n);

    // ---- layer 1 (MFMA GEMM with fused BN0+ReLU, then aggregation) ----
    k_gemm_hid_mfma<<<(n + 63) / 64, 256, 0, stream>>>((const uint4*)Bbf, stat0, stat0 + 128,
                                                       g0, be0, W1p, Abf, n, invn);
    k_aggregate128<<<(n * 64 + 255) / 256, 256, 0, stream>>>((const uint4*)Abf, epair, R, dinv,
                                                             (const float4*)b1, (uint4*)Bbf, n, e);
    k_bn_stats<<<(n + 255) / 256, 128, 0, stream>>>(Bbf, stat1, stat1 + 128, n);

    // ---- layer 2 (MFMA GEMM with fused BN1+ReLU, then aggregation to out) ----
    k_gemm_out_mfma<<<(n + 63) / 64, 256, 0, stream>>>((const uint4*)Bbf, stat1, stat1 + 128,
                                                       g1, be1, W2p, A16bf, n, invn);
    k_agg_out<<<(n * 8 + 255) / 256, 256, 0, stream>>>(A16bf, epair, R, dinv, b2, out, n, e);
}